// Round 5
// baseline (137.702 us; speedup 1.0000x reference)
//
#include <hip/hip_runtime.h>
#include <math.h>

#define DIM    512
#define RANK   4
#define NROW   2048   // BATCH * SEQ
#define DH     64
#define NH     16384  // NROW * HEADS
#define EPS    1e-8f
#define EPSDEN2 2.68435456f   // EPS * NH * NH  (softmax den ~= NH after expm1 split)

typedef short  bf16x8 __attribute__((ext_vector_type(8)));
typedef ushort u16x8  __attribute__((ext_vector_type(8)));
typedef float  f32x16 __attribute__((ext_vector_type(16)));

static __device__ __forceinline__ ushort f2bf(float f) {
    uint u = __float_as_uint(f);
    u += 0x7FFFu + ((u >> 16) & 1u);   // round-to-nearest-even
    return (ushort)(u >> 16);
}
static __device__ __forceinline__ float bf2f(ushort u) {
    return __uint_as_float((uint)u << 16);
}
static __device__ __forceinline__ uint cvtpk_bf16(float a, float b) {
    uint r;
    asm("v_cvt_pk_bf16_f32 %0, %1, %2" : "=v"(r) : "v"(a), "v"(b));
    return r;
}
static __device__ __forceinline__ void pl32swap(uint& a, uint& b) {
    asm("v_permlane32_swap_b32 %0, %1" : "+v"(a), "+v"(b));
}
static __device__ __forceinline__ uint pkh2(float a, float b) {
    _Float16 ha = (_Float16)a, hb = (_Float16)b;
    return (uint)__builtin_bit_cast(ushort, ha) | ((uint)__builtin_bit_cast(ushort, hb) << 16);
}
static __device__ __forceinline__ float h2f(ushort u) {
    return (float)__builtin_bit_cast(_Float16, u);
}
// expm1(s/8), |s| <= ~1.01: cubic, abs err ~1e-5 (<< bf16 P quantization 5e-4)
static __device__ __forceinline__ float expm1_8(float s) {
    float t = fmaf(s, 3.25520833e-4f, 0.0078125f);
    t = fmaf(s, t, 0.125f);
    return s * t;
}

// ---------------------------------------------------------------------------
// Kernel 1: TT projections q,k,v + L2-normalize q,k per head-row.
// Outputs: qq_b/kq_b bf16 [NH][DH], vvT bf16 [DH][NH].
// ---------------------------------------------------------------------------
__global__ __launch_bounds__(256) void proj_qkv(
    const float* __restrict__ x,
    const float* __restrict__ qA, const float* __restrict__ qB, const float* __restrict__ qb,
    const float* __restrict__ kA, const float* __restrict__ kB, const float* __restrict__ kb,
    const float* __restrict__ vA, const float* __restrict__ vB, const float* __restrict__ vb,
    ushort* __restrict__ qq_b, ushort* __restrict__ kq_b, ushort* __restrict__ vvT)
{
    __shared__ float qrow[DIM], krow[DIM], vrowS[DIM];
    __shared__ float wred[4][12];
    __shared__ float tvals[12];
    __shared__ float norms[16];

    const int n = blockIdx.x, t = threadIdx.x;
    const int wid = t >> 6, lane = t & 63;

    const float x0 = x[n * DIM + t];
    const float x1 = x[n * DIM + t + 256];

    float p[12];
    #pragma unroll
    for (int r = 0; r < 4; ++r) {
        p[r]     = x0 * qB[r * DIM + t] + x1 * qB[r * DIM + t + 256];
        p[4 + r] = x0 * kB[r * DIM + t] + x1 * kB[r * DIM + t + 256];
        p[8 + r] = x0 * vB[r * DIM + t] + x1 * vB[r * DIM + t + 256];
    }
    #pragma unroll
    for (int i = 0; i < 12; ++i) {
        #pragma unroll
        for (int off = 32; off; off >>= 1) p[i] += __shfl_xor(p[i], off);
    }
    if (lane == 0) {
        #pragma unroll
        for (int i = 0; i < 12; ++i) wred[wid][i] = p[i];
    }
    __syncthreads();
    if (t < 12) tvals[t] = wred[0][t] + wred[1][t] + wred[2][t] + wred[3][t];
    __syncthreads();

    float tq[4], tk[4], tv[4];
    #pragma unroll
    for (int r = 0; r < 4; ++r) { tq[r] = tvals[r]; tk[r] = tvals[4 + r]; tv[r] = tvals[8 + r]; }

    #pragma unroll
    for (int h = 0; h < 2; ++h) {
        const int o = t + h * 256;
        float yq = qb[o], yk = kb[o], yv = vb[o];
        #pragma unroll
        for (int r = 0; r < 4; ++r) {
            yq += tq[r] * qA[o * RANK + r];
            yk += tk[r] * kA[o * RANK + r];
            yv += tv[r] * vA[o * RANK + r];
        }
        qrow[o] = yq; krow[o] = yk; vrowS[o] = yv;
    }
    __syncthreads();

    {
        const int c = t >> 5, i2 = t & 31;
        const float a  = qrow[c * 64 + i2], b2 = qrow[c * 64 + i2 + 32];
        const float ak = krow[c * 64 + i2], bk = krow[c * 64 + i2 + 32];
        float s  = a * a + b2 * b2;
        float sk = ak * ak + bk * bk;
        #pragma unroll
        for (int off = 16; off; off >>= 1) { s += __shfl_xor(s, off); sk += __shfl_xor(sk, off); }
        if (i2 == 0) { norms[c] = sqrtf(s); norms[8 + c] = sqrtf(sk); }
    }
    __syncthreads();

    #pragma unroll
    for (int h = 0; h < 2; ++h) {
        const int o = t + h * 256;
        const int c = o >> 6;
        qq_b[n * DIM + o] = f2bf(qrow[o] / (norms[c] + EPS));
        kq_b[n * DIM + o] = f2bf(krow[o] / (norms[8 + c] + EPS));
    }

    // vvT[d][n*8 + j] = vrowS[j*64 + d]
    if (t < 64) {
        uint pk[4];
        #pragma unroll
        for (int i = 0; i < 4; ++i) {
            pk[i] = (uint)f2bf(vrowS[(2 * i) * 64 + t])
                  | ((uint)f2bf(vrowS[(2 * i + 1) * 64 + t]) << 16);
        }
        uint4 u4; u4.x = pk[0]; u4.y = pk[1]; u4.z = pk[2]; u4.w = pk[3];
        *(uint4*)((char*)vvT + (size_t)t * (NH * 2) + (size_t)n * 16) = u4;
    }
}

// ---------------------------------------------------------------------------
// Kernel 1b: Vsum[d] = sum over all NH keys of v[key][d]
// ---------------------------------------------------------------------------
__global__ __launch_bounds__(256) void vsum_kernel(
    const ushort* __restrict__ vvT, float* __restrict__ Vsum)
{
    __shared__ float red[4];
    const int d = blockIdx.x, t = threadIdx.x;
    const int wid = t >> 6, lane = t & 63;
    float s = 0.f;
    #pragma unroll
    for (int j = 0; j < 8; ++j) {
        const u16x8 u = *(const u16x8*)(vvT + (size_t)d * NH + (size_t)(j * 256 + t) * 8);
        #pragma unroll
        for (int e = 0; e < 8; ++e) s += bf2f(u[e]);
    }
    #pragma unroll
    for (int off = 32; off; off >>= 1) s += __shfl_xor(s, off);
    if (lane == 0) red[wid] = s;
    __syncthreads();
    if (t == 0) Vsum[d] = red[0] + red[1] + red[2] + red[3];
}

// ---------------------------------------------------------------------------
// Kernel 2: MFMA flash attention, P = expm1(s/8) (+1 term folded into Vsum).
// 8 waves x 64 q (2 strips of 32) = 512 q/block; grid = 32 q-blocks x nchunk.
// 128-key steps; K tile [128][128B], V^T tile [64][256B], both XOR-swizzled,
// double-buffered, staged global->reg->LDS, one barrier per step.
// Each K/V fragment read from LDS feeds 2 MFMAs (strip reuse).
// Writes fp16 partial numerators numpart[chunk][d][q].
// ---------------------------------------------------------------------------
__global__ __launch_bounds__(512, 2) void attn_kernel(
    const ushort* __restrict__ qq_b, const ushort* __restrict__ kq_b,
    const ushort* __restrict__ vvT, ushort* __restrict__ numpart, int log2nc)
{
    __shared__ __align__(16) char smem[2][32768];   // [buf][ K 16KB | V 16KB ]

    const int t = threadIdx.x;
    const int w = t >> 6, l = t & 63;
    const int l31 = l & 31, hi = l >> 5;
    const int chunk = blockIdx.x & ((1 << log2nc) - 1);
    const int q0 = (blockIdx.x >> log2nc) * 512 + w * 64;
    const int kchunk = NH >> log2nc;
    const int nstep = kchunk >> 7;
    const int kbase = chunk * kchunk;

    // staging geometry: K rows 128 x 8 slots of 16B; V rows 64 x 16 slots
    const int kr = t >> 3, ksl = t & 7;
    const int vr = t >> 4, vsl = t & 15;
    int kwo[2], vwo[2];
    size_t kgo[2], vgo[2];
    #pragma unroll
    for (int rep = 0; rep < 2; ++rep) {
        const int krow = rep * 64 + kr;
        kwo[rep] = krow * 128 + ((ksl ^ (krow & 7)) << 4);
        kgo[rep] = (size_t)(kbase + krow) * 128 + (ksl << 4);
        const int vrow = rep * 32 + vr;
        vwo[rep] = 16384 + vrow * 256 + ((vsl ^ (vrow & 7)) << 4);
        vgo[rep] = (size_t)vrow * (NH * 2) + (size_t)kbase * 2 + (vsl << 4);
    }

    // Q fragments (B-operand): strip sp, lane: col q = q0+sp*32+l31, k-slice w16*16+hi*8
    bf16x8 Qf[2][4];
    #pragma unroll
    for (int sp = 0; sp < 2; ++sp)
        #pragma unroll
        for (int w16 = 0; w16 < 4; ++w16)
            Qf[sp][w16] = *(const bf16x8*)((const char*)qq_b
                + (size_t)(q0 + sp * 32 + l31) * 128 + w16 * 32 + hi * 16);

    f32x16 acc[2][2];
    #pragma unroll
    for (int sp = 0; sp < 2; ++sp)
        #pragma unroll
        for (int dt = 0; dt < 2; ++dt)
            #pragma unroll
            for (int r = 0; r < 16; ++r) acc[sp][dt][r] = 0.f;

    // prologue: stage step 0, prefetch step 1 into regs
    uint4 kst[2], vst[2];
    #pragma unroll
    for (int rep = 0; rep < 2; ++rep) {
        kst[rep] = *(const uint4*)((const char*)kq_b + kgo[rep]);
        vst[rep] = *(const uint4*)((const char*)vvT + vgo[rep]);
    }
    #pragma unroll
    for (int rep = 0; rep < 2; ++rep) {
        *(uint4*)(smem[0] + kwo[rep]) = kst[rep];
        *(uint4*)(smem[0] + vwo[rep]) = vst[rep];
    }
    #pragma unroll
    for (int rep = 0; rep < 2; ++rep) {
        kst[rep] = *(const uint4*)((const char*)kq_b + kgo[rep] + 16384);
        vst[rep] = *(const uint4*)((const char*)vvT + vgo[rep] + 256);
    }
    __syncthreads();

    for (int s = 0; s < nstep; ++s) {
        const char* B = smem[s & 1];
        if (s + 1 < nstep) {                      // write step s+1's staged regs
            char* D = (char*)smem[(s & 1) ^ 1];
            #pragma unroll
            for (int rep = 0; rep < 2; ++rep) {
                *(uint4*)(D + kwo[rep]) = kst[rep];
                *(uint4*)(D + vwo[rep]) = vst[rep];
            }
        }
        if (s + 2 < nstep) {                      // early-issue step s+2's loads
            #pragma unroll
            for (int rep = 0; rep < 2; ++rep) {
                kst[rep] = *(const uint4*)((const char*)kq_b + kgo[rep] + (size_t)(s + 2) * 16384);
                vst[rep] = *(const uint4*)((const char*)vvT + vgo[rep] + (size_t)(s + 2) * 256);
            }
        }

        #pragma unroll
        for (int kt = 0; kt < 4; ++kt) {
            // K A-frags: lane: key-row kt*32+l31, dh-slice w16*16+hi*8
            bf16x8 kf[4];
            #pragma unroll
            for (int w16 = 0; w16 < 4; ++w16)
                kf[w16] = *(const bf16x8*)(B + kt * 4096 + l31 * 128
                          + ((((w16 << 1) | hi) ^ (l31 & 7)) << 4));

            union U { uint u[4]; bf16x8 v; };
            U pa[2][2];
            #pragma unroll
            for (int sp = 0; sp < 2; ++sp) {
                f32x16 st;
                #pragma unroll
                for (int r = 0; r < 16; ++r) st[r] = 0.f;
                __builtin_amdgcn_s_setprio(1);
                #pragma unroll
                for (int w16 = 0; w16 < 4; ++w16)
                    st = __builtin_amdgcn_mfma_f32_32x32x16_bf16(kf[w16], Qf[sp][w16], st, 0, 0, 0);
                __builtin_amdgcn_s_setprio(0);

                uint pk[8];
                #pragma unroll
                for (int j = 0; j < 8; ++j)
                    pk[j] = cvtpk_bf16(expm1_8(st[2 * j]), expm1_8(st[2 * j + 1]));
                pl32swap(pk[0], pk[2]); pl32swap(pk[1], pk[3]);
                pl32swap(pk[4], pk[6]); pl32swap(pk[5], pk[7]);
                #pragma unroll
                for (int j = 0; j < 4; ++j) { pa[sp][0].u[j] = pk[j]; pa[sp][1].u[j] = pk[4 + j]; }
            }

            __builtin_amdgcn_s_setprio(1);
            #pragma unroll
            for (int kw = 0; kw < 2; ++kw) {
                #pragma unroll
                for (int dt = 0; dt < 2; ++dt) {
                    const bf16x8 vf = *(const bf16x8*)(B + 16384 + (dt * 32 + l31) * 256
                        + ((((((kt << 1) | kw) << 1) | hi) ^ (l31 & 7)) << 4));
                    #pragma unroll
                    for (int sp = 0; sp < 2; ++sp)
                        acc[sp][dt] = __builtin_amdgcn_mfma_f32_32x32x16_bf16(pa[sp][kw].v, vf, acc[sp][dt], 0, 0, 0);
                }
            }
            __builtin_amdgcn_s_setprio(0);
        }
        __syncthreads();
    }

    // epilogue: acc D[q][d]: col d = dt*32+l31; regs 4g..4g+3 -> q = base+8g+4hi+0..3
    #pragma unroll
    for (int sp = 0; sp < 2; ++sp)
        #pragma unroll
        for (int dt = 0; dt < 2; ++dt) {
            const int d = dt * 32 + l31;
            #pragma unroll
            for (int g = 0; g < 4; ++g) {
                uint2 u2;
                u2.x = pkh2(acc[sp][dt][4 * g],     acc[sp][dt][4 * g + 1]);
                u2.y = pkh2(acc[sp][dt][4 * g + 2], acc[sp][dt][4 * g + 3]);
                const int q = q0 + sp * 32 + 8 * g + 4 * hi;
                *(uint2*)(numpart + (size_t)(chunk * 64 + d) * NH + q) = u2;
            }
        }
}

// ---------------------------------------------------------------------------
// Kernel 3: finalize = Vsum + chunk-reduce + measure (den-free) + TT out proj.
// measure = num^2 / (sum_d num^2 + EPS*NH^2)
// ---------------------------------------------------------------------------
__global__ __launch_bounds__(256) void finalize(
    const ushort* __restrict__ numpart, const float* __restrict__ Vsum,
    const float* __restrict__ oA, const float* __restrict__ oB,
    const float* __restrict__ ob, float* __restrict__ out, int nchunk)
{
    __shared__ float L[8][8][64];   // [qsub][chunk][d]
    __shared__ float csum[8];
    __shared__ float wred[4][4];
    __shared__ float tvals[4];

    const int n = blockIdx.x, t = threadIdx.x;
    const int wid = t >> 6, lane = t & 63;

    for (int cc = t >> 6; cc < nchunk; cc += 4) {
        const int dd = t & 63;
        const uint4 u = *(const uint4*)(numpart + (size_t)(cc * 64 + dd) * NH + n * 8);
        L[0][cc][dd] = h2f((ushort)(u.x & 0xffff));
        L[1][cc][dd] = h2f((ushort)(u.x >> 16));
        L[2][cc][dd] = h2f((ushort)(u.y & 0xffff));
        L[3][cc][dd] = h2f((ushort)(u.y >> 16));
        L[4][cc][dd] = h2f((ushort)(u.z & 0xffff));
        L[5][cc][dd] = h2f((ushort)(u.z >> 16));
        L[6][cc][dd] = h2f((ushort)(u.w & 0xffff));
        L[7][cc][dd] = h2f((ushort)(u.w >> 16));
    }
    __syncthreads();

    const float vs = Vsum[lane];
    float a0 = vs, a1 = vs;
    for (int c = 0; c < nchunk; ++c) { a0 += L[wid][c][lane]; a1 += L[wid + 4][c][lane]; }

    float s0 = a0 * a0, s1 = a1 * a1;
    #pragma unroll
    for (int off = 32; off; off >>= 1) { s0 += __shfl_xor(s0, off); s1 += __shfl_xor(s1, off); }
    if (lane == 0) { csum[wid] = s0; csum[4 + wid] = s1; }
    __syncthreads();

    const float m0 = a0 * a0 / (csum[wid] + EPSDEN2);
    const float m1 = a1 * a1 / (csum[4 + wid] + EPSDEN2);

    float p[4];
    #pragma unroll
    for (int r = 0; r < 4; ++r) p[r] = m0 * oB[r * DIM + t] + m1 * oB[r * DIM + t + 256];
    #pragma unroll
    for (int r = 0; r < 4; ++r) {
        #pragma unroll
        for (int off = 32; off; off >>= 1) p[r] += __shfl_xor(p[r], off);
    }
    if (lane == 0) {
        #pragma unroll
        for (int r = 0; r < 4; ++r) wred[wid][r] = p[r];
    }
    __syncthreads();
    if (t < 4) tvals[t] = wred[0][t] + wred[1][t] + wred[2][t] + wred[3][t];
    __syncthreads();

    #pragma unroll
    for (int h = 0; h < 2; ++h) {
        const int o = t + h * 256;
        float y = ob[o];
        #pragma unroll
        for (int r = 0; r < 4; ++r) y += tvals[r] * oA[o * RANK + r];
        out[n * DIM + o] = y;
    }
}

// ---------------------------------------------------------------------------
extern "C" void kernel_launch(void* const* d_in, const int* in_sizes, int n_in,
                              void* d_out, int out_size, void* d_ws, size_t ws_size,
                              hipStream_t stream) {
    const float* x  = (const float*)d_in[0];
    const float* qA = (const float*)d_in[1];
    const float* qB = (const float*)d_in[2];
    const float* qb = (const float*)d_in[3];
    const float* kA = (const float*)d_in[4];
    const float* kB = (const float*)d_in[5];
    const float* kb = (const float*)d_in[6];
    const float* vA = (const float*)d_in[7];
    const float* vB = (const float*)d_in[8];
    const float* vb = (const float*)d_in[9];
    const float* oA = (const float*)d_in[10];
    const float* oB = (const float*)d_in[11];
    const float* ob = (const float*)d_in[12];

    // ws layout: qq 2MB | kq 2MB | vvT 2MB | numpart nchunk*2MB | Vsum 256B
    const int use8 = (ws_size >= (size_t)23068928 + 256) ? 1 : 0;  // guard: fp16 numpart x8
    const int nchunk = use8 ? 8 : 4;
    const int log2nc = use8 ? 3 : 2;

    ushort* qq_b    = (ushort*)d_ws;
    ushort* kq_b    = qq_b + (size_t)NH * DH;
    ushort* vvT     = kq_b + (size_t)NH * DH;
    ushort* numpart = vvT + (size_t)NH * DH;
    float*  Vsum    = (float*)(numpart + (size_t)nchunk * DH * NH);
    float*  out     = (float*)d_out;

    proj_qkv<<<NROW, 256, 0, stream>>>(x, qA, qB, qb, kA, kB, kb, vA, vB, vb, qq_b, kq_b, vvT);
    vsum_kernel<<<DH, 256, 0, stream>>>(vvT, Vsum);
    attn_kernel<<<32 * nchunk, 512, 0, stream>>>(qq_b, kq_b, vvT, numpart, log2nc);
    finalize<<<NROW, 256, 0, stream>>>(numpart, Vsum, oA, oB, ob, out, nchunk);
}

// Round 6
// 129.329 us; speedup vs baseline: 1.0647x; 1.0647x over previous
//
#include <hip/hip_runtime.h>
#include <math.h>

#define DIM    512
#define RANK   4
#define NROW   2048   // BATCH * SEQ
#define DH     64
#define NH     16384  // NROW * HEADS
#define EPS    1e-8f
#define NCHUNK 8
#define KCHUNK 2048   // keys per block (NH / NCHUNK)
#define NSTEP  32     // KCHUNK / 64
#define EPSDEN2 2.68435456f   // EPS * NH^2 (den ~= NH; measure-cancellation, r3)
// kq pre-scale: y = s*(1+lam)/16, lam = 1/512 (minimax absorb of x^3/6 over |x|<=1/8)
#define KSCALE 0.0626220703125f

typedef short  bf16x8 __attribute__((ext_vector_type(8)));
typedef ushort u16x8  __attribute__((ext_vector_type(8)));
typedef float  f32x16 __attribute__((ext_vector_type(16)));

static __device__ __forceinline__ ushort f2bf(float f) {
    uint u = __float_as_uint(f);
    u += 0x7FFFu + ((u >> 16) & 1u);   // round-to-nearest-even
    return (ushort)(u >> 16);
}
static __device__ __forceinline__ float bf2f(ushort u) {
    return __uint_as_float((uint)u << 16);
}
static __device__ __forceinline__ uint cvtpk_bf16(float a, float b) {
    uint r;
    asm("v_cvt_pk_bf16_f32 %0, %1, %2" : "=v"(r) : "v"(a), "v"(b));
    return r;
}
static __device__ __forceinline__ void pl32swap(uint& a, uint& b) {
    asm("v_permlane32_swap_b32 %0, %1" : "+v"(a), "+v"(b));
}
static __device__ __forceinline__ uint pkh2(float a, float b) {
    _Float16 ha = (_Float16)a, hb = (_Float16)b;
    return (uint)__builtin_bit_cast(ushort, ha) | ((uint)__builtin_bit_cast(ushort, hb) << 16);
}
static __device__ __forceinline__ float h2f(ushort u) {
    return (float)__builtin_bit_cast(_Float16, u);
}

// ---------------------------------------------------------------------------
// Kernel 1: TT projections q,k,v + L2-normalize q,k per head-row.
// kq additionally scaled by KSCALE so the S-MFMA directly yields y.
// Outputs: qq_b/kq_b bf16 [NH][DH], vvT bf16 [DH][NH].
// ---------------------------------------------------------------------------
__global__ __launch_bounds__(256) void proj_qkv(
    const float* __restrict__ x,
    const float* __restrict__ qA, const float* __restrict__ qB, const float* __restrict__ qb,
    const float* __restrict__ kA, const float* __restrict__ kB, const float* __restrict__ kb,
    const float* __restrict__ vA, const float* __restrict__ vB, const float* __restrict__ vb,
    ushort* __restrict__ qq_b, ushort* __restrict__ kq_b, ushort* __restrict__ vvT)
{
    __shared__ float qrow[DIM], krow[DIM], vrowS[DIM];
    __shared__ float wred[4][12];
    __shared__ float tvals[12];
    __shared__ float norms[16];

    const int n = blockIdx.x, t = threadIdx.x;
    const int wid = t >> 6, lane = t & 63;

    const float x0 = x[n * DIM + t];
    const float x1 = x[n * DIM + t + 256];

    float p[12];
    #pragma unroll
    for (int r = 0; r < 4; ++r) {
        p[r]     = x0 * qB[r * DIM + t] + x1 * qB[r * DIM + t + 256];
        p[4 + r] = x0 * kB[r * DIM + t] + x1 * kB[r * DIM + t + 256];
        p[8 + r] = x0 * vB[r * DIM + t] + x1 * vB[r * DIM + t + 256];
    }
    #pragma unroll
    for (int i = 0; i < 12; ++i) {
        #pragma unroll
        for (int off = 32; off; off >>= 1) p[i] += __shfl_xor(p[i], off);
    }
    if (lane == 0) {
        #pragma unroll
        for (int i = 0; i < 12; ++i) wred[wid][i] = p[i];
    }
    __syncthreads();
    if (t < 12) tvals[t] = wred[0][t] + wred[1][t] + wred[2][t] + wred[3][t];
    __syncthreads();

    float tq[4], tk[4], tv[4];
    #pragma unroll
    for (int r = 0; r < 4; ++r) { tq[r] = tvals[r]; tk[r] = tvals[4 + r]; tv[r] = tvals[8 + r]; }

    #pragma unroll
    for (int h = 0; h < 2; ++h) {
        const int o = t + h * 256;
        float yq = qb[o], yk = kb[o], yv = vb[o];
        #pragma unroll
        for (int r = 0; r < 4; ++r) {
            yq += tq[r] * qA[o * RANK + r];
            yk += tk[r] * kA[o * RANK + r];
            yv += tv[r] * vA[o * RANK + r];
        }
        qrow[o] = yq; krow[o] = yk; vrowS[o] = yv;
    }
    __syncthreads();

    {
        const int c = t >> 5, i2 = t & 31;
        const float a  = qrow[c * 64 + i2], b2 = qrow[c * 64 + i2 + 32];
        const float ak = krow[c * 64 + i2], bk = krow[c * 64 + i2 + 32];
        float s  = a * a + b2 * b2;
        float sk = ak * ak + bk * bk;
        #pragma unroll
        for (int off = 16; off; off >>= 1) { s += __shfl_xor(s, off); sk += __shfl_xor(sk, off); }
        if (i2 == 0) { norms[c] = sqrtf(s); norms[8 + c] = sqrtf(sk); }
    }
    __syncthreads();

    #pragma unroll
    for (int h = 0; h < 2; ++h) {
        const int o = t + h * 256;
        const int c = o >> 6;
        qq_b[n * DIM + o] = f2bf(qrow[o] / (norms[c] + EPS));
        kq_b[n * DIM + o] = f2bf(krow[o] / (norms[8 + c] + EPS) * KSCALE);
    }

    // vvT[d][n*8 + j] = vrowS[j*64 + d]
    if (t < 64) {
        uint pk[4];
        #pragma unroll
        for (int i = 0; i < 4; ++i) {
            pk[i] = (uint)f2bf(vrowS[(2 * i) * 64 + t])
                  | ((uint)f2bf(vrowS[(2 * i + 1) * 64 + t]) << 16);
        }
        uint4 u4; u4.x = pk[0]; u4.y = pk[1]; u4.z = pk[2]; u4.w = pk[3];
        *(uint4*)((char*)vvT + (size_t)t * (NH * 2) + (size_t)n * 16) = u4;
    }
}

// ---------------------------------------------------------------------------
// Kernel 1b: Vsum[d] = sum over all NH keys of v[key][d]
// ---------------------------------------------------------------------------
__global__ __launch_bounds__(256) void vsum_kernel(
    const ushort* __restrict__ vvT, float* __restrict__ Vsum)
{
    __shared__ float red[4];
    const int d = blockIdx.x, t = threadIdx.x;
    const int wid = t >> 6, lane = t & 63;
    float s = 0.f;
    #pragma unroll
    for (int j = 0; j < 8; ++j) {
        const u16x8 u = *(const u16x8*)(vvT + (size_t)d * NH + (size_t)(j * 256 + t) * 8);
        #pragma unroll
        for (int e = 0; e < 8; ++e) s += bf2f(u[e]);
    }
    #pragma unroll
    for (int off = 32; off; off >>= 1) s += __shfl_xor(s, off);
    if (lane == 0) red[wid] = s;
    __syncthreads();
    if (t == 0) Vsum[d] = red[0] + red[1] + red[2] + red[3];
}

// ---------------------------------------------------------------------------
// Kernel 2: MFMA flash attention. Weight w = 1 + 2*(y + y^2), y = s(1+lam)/16
// (the "1" is Vsum, folded in finalize; the 2 is applied in finalize).
// 4 waves x 64 q (2 strips) = 256 q/block; grid = 64 q-blocks x 8 chunks
// = 512 blocks = 2 independent barrier domains per CU.
// 64-key steps; K tile [64][128B] + V^T tile [64][128B], XOR-swizzled,
// double-buffered, reg-staged with s+2 prefetch, one barrier per step.
// All loop bounds compile-time. Writes fp16 numpart[chunk][d][q].
// ---------------------------------------------------------------------------
__global__ __launch_bounds__(256, 2) void attn_kernel(
    const ushort* __restrict__ qq_b, const ushort* __restrict__ kq_b,
    const ushort* __restrict__ vvT, ushort* __restrict__ numpart)
{
    __shared__ __align__(16) char smem[2][16384];   // [buf][ K 8KB | V 8KB ]

    const int t = threadIdx.x;
    const int w = t >> 6, l = t & 63;
    const int l31 = l & 31, hi = l >> 5;
    const int chunk = blockIdx.x & 7;               // chunk == XCD (heuristic)
    const int q0 = (blockIdx.x >> 3) * 256 + w * 64;
    const int kbase = chunk * KCHUNK;

    // staging: thread t stages rows (r*32 + t>>3), 16B slot t&7, for K and V
    const int sr = t >> 3, ssl = t & 7;
    int kwo[2], vwo[2];
    size_t kgo[2], vgo[2];
    #pragma unroll
    for (int rep = 0; rep < 2; ++rep) {
        const int row = rep * 32 + sr;
        const int wsl = (ssl ^ (row & 7)) << 4;
        kwo[rep] = row * 128 + wsl;
        vwo[rep] = 8192 + row * 128 + wsl;
        kgo[rep] = (size_t)(kbase + row) * 128 + (ssl << 4);
        vgo[rep] = (size_t)row * (NH * 2) + (size_t)kbase * 2 + (ssl << 4);
    }

    // Q fragments (B-operand): strip sp, lane: col q = q0+sp*32+l31,
    // k-elems w16*16 + hi*8 .. +8
    bf16x8 Qf[2][4];
    #pragma unroll
    for (int sp = 0; sp < 2; ++sp)
        #pragma unroll
        for (int w16 = 0; w16 < 4; ++w16)
            Qf[sp][w16] = *(const bf16x8*)((const char*)qq_b
                + (size_t)(q0 + sp * 32 + l31) * 128 + w16 * 32 + hi * 16);

    f32x16 acc[2][2];
    #pragma unroll
    for (int sp = 0; sp < 2; ++sp)
        #pragma unroll
        for (int dt = 0; dt < 2; ++dt)
            #pragma unroll
            for (int r = 0; r < 16; ++r) acc[sp][dt][r] = 0.f;

    // prologue: stage step 0, prefetch step 1 into regs
    uint4 kst[2], vst[2];
    #pragma unroll
    for (int rep = 0; rep < 2; ++rep) {
        kst[rep] = *(const uint4*)((const char*)kq_b + kgo[rep]);
        vst[rep] = *(const uint4*)((const char*)vvT + vgo[rep]);
    }
    #pragma unroll
    for (int rep = 0; rep < 2; ++rep) {
        *(uint4*)(smem[0] + kwo[rep]) = kst[rep];
        *(uint4*)(smem[0] + vwo[rep]) = vst[rep];
    }
    #pragma unroll
    for (int rep = 0; rep < 2; ++rep) {
        kst[rep] = *(const uint4*)((const char*)kq_b + kgo[rep] + 8192);
        vst[rep] = *(const uint4*)((const char*)vvT + vgo[rep] + 128);
    }
    __syncthreads();

    for (int s = 0; s < NSTEP; ++s) {
        const char* B = smem[s & 1];
        if (s + 1 < NSTEP) {                      // write step s+1's staged regs
            char* D = (char*)smem[(s & 1) ^ 1];
            #pragma unroll
            for (int rep = 0; rep < 2; ++rep) {
                *(uint4*)(D + kwo[rep]) = kst[rep];
                *(uint4*)(D + vwo[rep]) = vst[rep];
            }
        }
        if (s + 2 < NSTEP) {                      // early-issue step s+2's loads
            #pragma unroll
            for (int rep = 0; rep < 2; ++rep) {
                kst[rep] = *(const uint4*)((const char*)kq_b + kgo[rep] + (size_t)(s + 2) * 8192);
                vst[rep] = *(const uint4*)((const char*)vvT + vgo[rep] + (size_t)(s + 2) * 128);
            }
        }

        #pragma unroll
        for (int kt = 0; kt < 2; ++kt) {
            // K A-frags: lane: key-row kt*32+l31, dh-slice w16*16+hi*8
            bf16x8 kf[4];
            #pragma unroll
            for (int w16 = 0; w16 < 4; ++w16)
                kf[w16] = *(const bf16x8*)(B + kt * 4096 + l31 * 128
                          + ((((w16 << 1) | hi) ^ (l31 & 7)) << 4));

            union U { uint u[4]; bf16x8 v; };
            U pa[2][2];
            #pragma unroll
            for (int sp = 0; sp < 2; ++sp) {
                f32x16 st;
                #pragma unroll
                for (int r = 0; r < 16; ++r) st[r] = 0.f;
                __builtin_amdgcn_s_setprio(1);
                #pragma unroll
                for (int w16 = 0; w16 < 4; ++w16)
                    st = __builtin_amdgcn_mfma_f32_32x32x16_bf16(kf[w16], Qf[sp][w16], st, 0, 0, 0);
                __builtin_amdgcn_s_setprio(0);

                // P'' = y + y^2 = fma(y,y,y): ONE VALU op per element
                uint pk[8];
                #pragma unroll
                for (int j = 0; j < 8; ++j)
                    pk[j] = cvtpk_bf16(fmaf(st[2 * j], st[2 * j], st[2 * j]),
                                       fmaf(st[2 * j + 1], st[2 * j + 1], st[2 * j + 1]));
                pl32swap(pk[0], pk[2]); pl32swap(pk[1], pk[3]);
                pl32swap(pk[4], pk[6]); pl32swap(pk[5], pk[7]);
                #pragma unroll
                for (int j = 0; j < 4; ++j) { pa[sp][0].u[j] = pk[j]; pa[sp][1].u[j] = pk[4 + j]; }
            }

            __builtin_amdgcn_s_setprio(1);
            #pragma unroll
            for (int kw = 0; kw < 2; ++kw) {
                #pragma unroll
                for (int dt = 0; dt < 2; ++dt) {
                    const bf16x8 vf = *(const bf16x8*)(B + 8192 + (dt * 32 + l31) * 128
                        + ((((kt << 2) | (kw << 1) | hi) ^ (l31 & 7)) << 4));
                    #pragma unroll
                    for (int sp = 0; sp < 2; ++sp)
                        acc[sp][dt] = __builtin_amdgcn_mfma_f32_32x32x16_bf16(pa[sp][kw].v, vf, acc[sp][dt], 0, 0, 0);
                }
            }
            __builtin_amdgcn_s_setprio(0);
        }
        __syncthreads();
    }

    // epilogue: acc D[q][d]: col d = dt*32+l31; regs 4g..4g+3 -> q = base+8g+4hi+0..3
    #pragma unroll
    for (int sp = 0; sp < 2; ++sp)
        #pragma unroll
        for (int dt = 0; dt < 2; ++dt) {
            const int d = dt * 32 + l31;
            #pragma unroll
            for (int g = 0; g < 4; ++g) {
                uint2 u2;
                u2.x = pkh2(acc[sp][dt][4 * g],     acc[sp][dt][4 * g + 1]);
                u2.y = pkh2(acc[sp][dt][4 * g + 2], acc[sp][dt][4 * g + 3]);
                const int q = q0 + sp * 32 + 8 * g + 4 * hi;
                *(uint2*)(numpart + (size_t)(chunk * 64 + d) * NH + q) = u2;
            }
        }
}

// ---------------------------------------------------------------------------
// Kernel 3: finalize = Vsum + 2*chunk-sum + measure (den-free) + TT out proj.
// measure = num^2 / (sum_d num^2 + EPS*NH^2)
// ---------------------------------------------------------------------------
__global__ __launch_bounds__(256) void finalize(
    const ushort* __restrict__ numpart, const float* __restrict__ Vsum,
    const float* __restrict__ oA, const float* __restrict__ oB,
    const float* __restrict__ ob, float* __restrict__ out)
{
    __shared__ float L[8][NCHUNK][64];   // [qsub][chunk][d]
    __shared__ float csum[8];
    __shared__ float wred[4][4];
    __shared__ float tvals[4];

    const int n = blockIdx.x, t = threadIdx.x;
    const int wid = t >> 6, lane = t & 63;

    #pragma unroll
    for (int ci = 0; ci < 2; ++ci) {
        const int cc = (t >> 6) + ci * 4;
        const int dd = t & 63;
        const uint4 u = *(const uint4*)(numpart + (size_t)(cc * 64 + dd) * NH + n * 8);
        L[0][cc][dd] = h2f((ushort)(u.x & 0xffff));
        L[1][cc][dd] = h2f((ushort)(u.x >> 16));
        L[2][cc][dd] = h2f((ushort)(u.y & 0xffff));
        L[3][cc][dd] = h2f((ushort)(u.y >> 16));
        L[4][cc][dd] = h2f((ushort)(u.z & 0xffff));
        L[5][cc][dd] = h2f((ushort)(u.z >> 16));
        L[6][cc][dd] = h2f((ushort)(u.w & 0xffff));
        L[7][cc][dd] = h2f((ushort)(u.w >> 16));
    }
    __syncthreads();

    const float vs = Vsum[lane];
    float b0 = 0.f, b1 = 0.f;
    #pragma unroll
    for (int c = 0; c < NCHUNK; ++c) { b0 += L[wid][c][lane]; b1 += L[wid + 4][c][lane]; }
    const float a0 = vs + 2.f * b0;
    const float a1 = vs + 2.f * b1;

    float s0 = a0 * a0, s1 = a1 * a1;
    #pragma unroll
    for (int off = 32; off; off >>= 1) { s0 += __shfl_xor(s0, off); s1 += __shfl_xor(s1, off); }
    if (lane == 0) { csum[wid] = s0; csum[4 + wid] = s1; }
    __syncthreads();

    const float m0 = a0 * a0 / (csum[wid] + EPSDEN2);
    const float m1 = a1 * a1 / (csum[4 + wid] + EPSDEN2);

    float p[4];
    #pragma unroll
    for (int r = 0; r < 4; ++r) p[r] = m0 * oB[r * DIM + t] + m1 * oB[r * DIM + t + 256];
    #pragma unroll
    for (int r = 0; r < 4; ++r) {
        #pragma unroll
        for (int off = 32; off; off >>= 1) p[r] += __shfl_xor(p[r], off);
    }
    if (lane == 0) {
        #pragma unroll
        for (int r = 0; r < 4; ++r) wred[wid][r] = p[r];
    }
    __syncthreads();
    if (t < 4) tvals[t] = wred[0][t] + wred[1][t] + wred[2][t] + wred[3][t];
    __syncthreads();

    #pragma unroll
    for (int h = 0; h < 2; ++h) {
        const int o = t + h * 256;
        float y = ob[o];
        #pragma unroll
        for (int r = 0; r < 4; ++r) y += tvals[r] * oA[o * RANK + r];
        out[n * DIM + o] = y;
    }
}

// ---------------------------------------------------------------------------
extern "C" void kernel_launch(void* const* d_in, const int* in_sizes, int n_in,
                              void* d_out, int out_size, void* d_ws, size_t ws_size,
                              hipStream_t stream) {
    const float* x  = (const float*)d_in[0];
    const float* qA = (const float*)d_in[1];
    const float* qB = (const float*)d_in[2];
    const float* qb = (const float*)d_in[3];
    const float* kA = (const float*)d_in[4];
    const float* kB = (const float*)d_in[5];
    const float* kb = (const float*)d_in[6];
    const float* vA = (const float*)d_in[7];
    const float* vB = (const float*)d_in[8];
    const float* vb = (const float*)d_in[9];
    const float* oA = (const float*)d_in[10];
    const float* oB = (const float*)d_in[11];
    const float* ob = (const float*)d_in[12];

    // ws: qq 2MB | kq 2MB | vvT 2MB | numpart fp16 [8][64][NH] 16MB | Vsum 256B
    ushort* qq_b    = (ushort*)d_ws;
    ushort* kq_b    = qq_b + (size_t)NH * DH;
    ushort* vvT     = kq_b + (size_t)NH * DH;
    ushort* numpart = vvT + (size_t)NH * DH;
    float*  Vsum    = (float*)(numpart + (size_t)NCHUNK * DH * NH);
    float*  out     = (float*)d_out;

    proj_qkv<<<NROW, 256, 0, stream>>>(x, qA, qB, qb, kA, kB, kb, vA, vB, vb, qq_b, kq_b, vvT);
    vsum_kernel<<<DH, 256, 0, stream>>>(vvT, Vsum);
    attn_kernel<<<64 * NCHUNK, 256, 0, stream>>>(qq_b, kq_b, vvT, numpart);
    finalize<<<NROW, 256, 0, stream>>>(numpart, Vsum, oA, oB, ob, out);
}

// Round 7
// 128.953 us; speedup vs baseline: 1.0679x; 1.0029x over previous
//
#include <hip/hip_runtime.h>
#include <math.h>

#define DIM    512
#define RANK   4
#define NROW   2048   // BATCH * SEQ
#define DH     64
#define NH     16384  // NROW * HEADS
#define EPS    1e-8f
#define NCHUNK 8
#define KCHUNK 2048   // keys per block (NH / NCHUNK)
#define NSTEP  32     // KCHUNK / 64
#define EPSDEN2 2.68435456f   // EPS * NH^2 (den ~= NH; measure-cancellation, r3)
// kq pre-scale: y = s*(1+lam)/16, lam = 1/512 (minimax absorb of x^3/6 over |x|<=1/8)
#define KSCALE 0.0626220703125f

typedef short  bf16x8 __attribute__((ext_vector_type(8)));
typedef ushort u16x8  __attribute__((ext_vector_type(8)));
typedef float  f32x16 __attribute__((ext_vector_type(16)));

static __device__ __forceinline__ ushort f2bf(float f) {
    uint u = __float_as_uint(f);
    u += 0x7FFFu + ((u >> 16) & 1u);   // round-to-nearest-even
    return (ushort)(u >> 16);
}
static __device__ __forceinline__ float bf2f(ushort u) {
    return __uint_as_float((uint)u << 16);
}
static __device__ __forceinline__ uint cvtpk_bf16(float a, float b) {
    uint r;
    asm("v_cvt_pk_bf16_f32 %0, %1, %2" : "=v"(r) : "v"(a), "v"(b));
    return r;
}
static __device__ __forceinline__ void pl32swap(uint& a, uint& b) {
    asm("v_permlane32_swap_b32 %0, %1" : "+v"(a), "+v"(b));
}
static __device__ __forceinline__ uint pkh2(float a, float b) {
    _Float16 ha = (_Float16)a, hb = (_Float16)b;
    return (uint)__builtin_bit_cast(ushort, ha) | ((uint)__builtin_bit_cast(ushort, hb) << 16);
}
static __device__ __forceinline__ float h2f(ushort u) {
    return (float)__builtin_bit_cast(_Float16, u);
}
// barrier that does NOT drain vmcnt: LDS visibility only (lgkmcnt), so
// register-prefetch global loads stay in flight across the barrier (T4).
static __device__ __forceinline__ void barrier_lgkm() {
    asm volatile("s_waitcnt lgkmcnt(0)" ::: "memory");
    __builtin_amdgcn_s_barrier();
}

// ---------------------------------------------------------------------------
// Kernel 1: TT projections q,k,v + L2-normalize q,k per head-row.
// kq additionally scaled by KSCALE so the S-MFMA directly yields y.
// Outputs: qq_b/kq_b bf16 [NH][DH], vvT bf16 [DH][NH].
// ---------------------------------------------------------------------------
__global__ __launch_bounds__(256) void proj_qkv(
    const float* __restrict__ x,
    const float* __restrict__ qA, const float* __restrict__ qB, const float* __restrict__ qb,
    const float* __restrict__ kA, const float* __restrict__ kB, const float* __restrict__ kb,
    const float* __restrict__ vA, const float* __restrict__ vB, const float* __restrict__ vb,
    ushort* __restrict__ qq_b, ushort* __restrict__ kq_b, ushort* __restrict__ vvT)
{
    __shared__ float qrow[DIM], krow[DIM], vrowS[DIM];
    __shared__ float wred[4][12];
    __shared__ float tvals[12];
    __shared__ float norms[16];

    const int n = blockIdx.x, t = threadIdx.x;
    const int wid = t >> 6, lane = t & 63;

    const float x0 = x[n * DIM + t];
    const float x1 = x[n * DIM + t + 256];

    float p[12];
    #pragma unroll
    for (int r = 0; r < 4; ++r) {
        p[r]     = x0 * qB[r * DIM + t] + x1 * qB[r * DIM + t + 256];
        p[4 + r] = x0 * kB[r * DIM + t] + x1 * kB[r * DIM + t + 256];
        p[8 + r] = x0 * vB[r * DIM + t] + x1 * vB[r * DIM + t + 256];
    }
    #pragma unroll
    for (int i = 0; i < 12; ++i) {
        #pragma unroll
        for (int off = 32; off; off >>= 1) p[i] += __shfl_xor(p[i], off);
    }
    if (lane == 0) {
        #pragma unroll
        for (int i = 0; i < 12; ++i) wred[wid][i] = p[i];
    }
    __syncthreads();
    if (t < 12) tvals[t] = wred[0][t] + wred[1][t] + wred[2][t] + wred[3][t];
    __syncthreads();

    float tq[4], tk[4], tv[4];
    #pragma unroll
    for (int r = 0; r < 4; ++r) { tq[r] = tvals[r]; tk[r] = tvals[4 + r]; tv[r] = tvals[8 + r]; }

    #pragma unroll
    for (int h = 0; h < 2; ++h) {
        const int o = t + h * 256;
        float yq = qb[o], yk = kb[o], yv = vb[o];
        #pragma unroll
        for (int r = 0; r < 4; ++r) {
            yq += tq[r] * qA[o * RANK + r];
            yk += tk[r] * kA[o * RANK + r];
            yv += tv[r] * vA[o * RANK + r];
        }
        qrow[o] = yq; krow[o] = yk; vrowS[o] = yv;
    }
    __syncthreads();

    {
        const int c = t >> 5, i2 = t & 31;
        const float a  = qrow[c * 64 + i2], b2 = qrow[c * 64 + i2 + 32];
        const float ak = krow[c * 64 + i2], bk = krow[c * 64 + i2 + 32];
        float s  = a * a + b2 * b2;
        float sk = ak * ak + bk * bk;
        #pragma unroll
        for (int off = 16; off; off >>= 1) { s += __shfl_xor(s, off); sk += __shfl_xor(sk, off); }
        if (i2 == 0) { norms[c] = sqrtf(s); norms[8 + c] = sqrtf(sk); }
    }
    __syncthreads();

    #pragma unroll
    for (int h = 0; h < 2; ++h) {
        const int o = t + h * 256;
        const int c = o >> 6;
        qq_b[n * DIM + o] = f2bf(qrow[o] / (norms[c] + EPS));
        kq_b[n * DIM + o] = f2bf(krow[o] / (norms[8 + c] + EPS) * KSCALE);
    }

    // vvT[d][n*8 + j] = vrowS[j*64 + d]
    if (t < 64) {
        uint pk[4];
        #pragma unroll
        for (int i = 0; i < 4; ++i) {
            pk[i] = (uint)f2bf(vrowS[(2 * i) * 64 + t])
                  | ((uint)f2bf(vrowS[(2 * i + 1) * 64 + t]) << 16);
        }
        uint4 u4; u4.x = pk[0]; u4.y = pk[1]; u4.z = pk[2]; u4.w = pk[3];
        *(uint4*)((char*)vvT + (size_t)t * (NH * 2) + (size_t)n * 16) = u4;
    }
}

// ---------------------------------------------------------------------------
// Kernel 1b: Vsum[d] = sum over all NH keys of v[key][d]
// ---------------------------------------------------------------------------
__global__ __launch_bounds__(256) void vsum_kernel(
    const ushort* __restrict__ vvT, float* __restrict__ Vsum)
{
    __shared__ float red[4];
    const int d = blockIdx.x, t = threadIdx.x;
    const int wid = t >> 6, lane = t & 63;
    float s = 0.f;
    #pragma unroll
    for (int j = 0; j < 8; ++j) {
        const u16x8 u = *(const u16x8*)(vvT + (size_t)d * NH + (size_t)(j * 256 + t) * 8);
        #pragma unroll
        for (int e = 0; e < 8; ++e) s += bf2f(u[e]);
    }
    #pragma unroll
    for (int off = 32; off; off >>= 1) s += __shfl_xor(s, off);
    if (lane == 0) red[wid] = s;
    __syncthreads();
    if (t == 0) Vsum[d] = red[0] + red[1] + red[2] + red[3];
}

// ---------------------------------------------------------------------------
// Kernel 2: MFMA flash attention. Weight w = 1 + 2*(y + y^2), y = s(1+lam)/16
// (the "1" is Vsum, folded in finalize; the 2 is applied in finalize).
// 4 waves x 64 q (2 strips) = 256 q/block; grid = 64 q-blocks x 8 chunks
// = 512 blocks = 2 independent barrier domains per CU.
// 64-key steps; double-buffered LDS, reg-staged with s+2 prefetch.
// KEY CHANGE vs r6: barrier is lgkmcnt-only (raw s_barrier) so prefetch
// loads stay in flight across steps; compiler emits counted vmcnt before
// the dependent ds_writes instead of draining to 0 at every barrier.
// ---------------------------------------------------------------------------
__global__ __launch_bounds__(256, 2) void attn_kernel(
    const ushort* __restrict__ qq_b, const ushort* __restrict__ kq_b,
    const ushort* __restrict__ vvT, ushort* __restrict__ numpart)
{
    __shared__ __align__(16) char smem[2][16384];   // [buf][ K 8KB | V 8KB ]

    const int t = threadIdx.x;
    const int w = t >> 6, l = t & 63;
    const int l31 = l & 31, hi = l >> 5;
    const int chunk = blockIdx.x & 7;
    const int q0 = (blockIdx.x >> 3) * 256 + w * 64;
    const int kbase = chunk * KCHUNK;

    // staging: thread t stages rows (rep*32 + t>>3), 16B slot t&7, K and V
    const int sr = t >> 3, ssl = t & 7;
    int kwo[2], vwo[2];
    size_t kgo[2], vgo[2];
    #pragma unroll
    for (int rep = 0; rep < 2; ++rep) {
        const int row = rep * 32 + sr;
        const int wsl = (ssl ^ (row & 7)) << 4;
        kwo[rep] = row * 128 + wsl;
        vwo[rep] = 8192 + row * 128 + wsl;
        kgo[rep] = (size_t)(kbase + row) * 128 + (ssl << 4);
        vgo[rep] = (size_t)row * (NH * 2) + (size_t)kbase * 2 + (ssl << 4);
    }

    // Q fragments (B-operand): strip sp, lane: col q = q0+sp*32+l31,
    // k-elems w16*16 + hi*8 .. +8
    bf16x8 Qf[2][4];
    #pragma unroll
    for (int sp = 0; sp < 2; ++sp)
        #pragma unroll
        for (int w16 = 0; w16 < 4; ++w16)
            Qf[sp][w16] = *(const bf16x8*)((const char*)qq_b
                + (size_t)(q0 + sp * 32 + l31) * 128 + w16 * 32 + hi * 16);

    f32x16 acc[2][2];
    #pragma unroll
    for (int sp = 0; sp < 2; ++sp)
        #pragma unroll
        for (int dt = 0; dt < 2; ++dt)
            #pragma unroll
            for (int r = 0; r < 16; ++r) acc[sp][dt][r] = 0.f;

    // prologue: stage step 0, prefetch step 1 into regs
    uint4 kst[2], vst[2];
    #pragma unroll
    for (int rep = 0; rep < 2; ++rep) {
        kst[rep] = *(const uint4*)((const char*)kq_b + kgo[rep]);
        vst[rep] = *(const uint4*)((const char*)vvT + vgo[rep]);
    }
    #pragma unroll
    for (int rep = 0; rep < 2; ++rep) {
        *(uint4*)(smem[0] + kwo[rep]) = kst[rep];
        *(uint4*)(smem[0] + vwo[rep]) = vst[rep];
    }
    #pragma unroll
    for (int rep = 0; rep < 2; ++rep) {
        kst[rep] = *(const uint4*)((const char*)kq_b + kgo[rep] + 8192);
        vst[rep] = *(const uint4*)((const char*)vvT + vgo[rep] + 128);
    }
    barrier_lgkm();

    for (int s = 0; s < NSTEP; ++s) {
        const char* B = smem[s & 1];
        if (s + 1 < NSTEP) {                      // write step s+1's staged regs
            char* D = (char*)smem[(s & 1) ^ 1];
            #pragma unroll
            for (int rep = 0; rep < 2; ++rep) {
                *(uint4*)(D + kwo[rep]) = kst[rep];
                *(uint4*)(D + vwo[rep]) = vst[rep];
            }
        }
        if (s + 2 < NSTEP) {                      // early-issue step s+2's loads
            #pragma unroll
            for (int rep = 0; rep < 2; ++rep) {
                kst[rep] = *(const uint4*)((const char*)kq_b + kgo[rep] + (size_t)(s + 2) * 8192);
                vst[rep] = *(const uint4*)((const char*)vvT + vgo[rep] + (size_t)(s + 2) * 128);
            }
        }

        #pragma unroll
        for (int kt = 0; kt < 2; ++kt) {
            // K A-frags: lane: key-row kt*32+l31, dh-slice w16*16+hi*8
            bf16x8 kf[4];
            #pragma unroll
            for (int w16 = 0; w16 < 4; ++w16)
                kf[w16] = *(const bf16x8*)(B + kt * 4096 + l31 * 128
                          + ((((w16 << 1) | hi) ^ (l31 & 7)) << 4));

            union U { uint u[4]; bf16x8 v; };
            U pa[2][2];
            #pragma unroll
            for (int sp = 0; sp < 2; ++sp) {
                f32x16 st;
                #pragma unroll
                for (int r = 0; r < 16; ++r) st[r] = 0.f;
                __builtin_amdgcn_s_setprio(1);
                #pragma unroll
                for (int w16 = 0; w16 < 4; ++w16)
                    st = __builtin_amdgcn_mfma_f32_32x32x16_bf16(kf[w16], Qf[sp][w16], st, 0, 0, 0);
                __builtin_amdgcn_s_setprio(0);

                // P'' = y + y^2 = fma(y,y,y): ONE VALU op per element
                uint pk[8];
                #pragma unroll
                for (int j = 0; j < 8; ++j)
                    pk[j] = cvtpk_bf16(fmaf(st[2 * j], st[2 * j], st[2 * j]),
                                       fmaf(st[2 * j + 1], st[2 * j + 1], st[2 * j + 1]));
                pl32swap(pk[0], pk[2]); pl32swap(pk[1], pk[3]);
                pl32swap(pk[4], pk[6]); pl32swap(pk[5], pk[7]);
                #pragma unroll
                for (int j = 0; j < 4; ++j) { pa[sp][0].u[j] = pk[j]; pa[sp][1].u[j] = pk[4 + j]; }
            }

            __builtin_amdgcn_s_setprio(1);
            #pragma unroll
            for (int kw = 0; kw < 2; ++kw) {
                #pragma unroll
                for (int dt = 0; dt < 2; ++dt) {
                    const bf16x8 vf = *(const bf16x8*)(B + 8192 + (dt * 32 + l31) * 128
                        + ((((kt << 2) | (kw << 1) | hi) ^ (l31 & 7)) << 4));
                    #pragma unroll
                    for (int sp = 0; sp < 2; ++sp)
                        acc[sp][dt] = __builtin_amdgcn_mfma_f32_32x32x16_bf16(pa[sp][kw].v, vf, acc[sp][dt], 0, 0, 0);
                }
            }
            __builtin_amdgcn_s_setprio(0);
        }
        barrier_lgkm();
    }

    // epilogue: acc D[q][d]: col d = dt*32+l31; regs 4g..4g+3 -> q = base+8g+4hi+0..3
    #pragma unroll
    for (int sp = 0; sp < 2; ++sp)
        #pragma unroll
        for (int dt = 0; dt < 2; ++dt) {
            const int d = dt * 32 + l31;
            #pragma unroll
            for (int g = 0; g < 4; ++g) {
                uint2 u2;
                u2.x = pkh2(acc[sp][dt][4 * g],     acc[sp][dt][4 * g + 1]);
                u2.y = pkh2(acc[sp][dt][4 * g + 2], acc[sp][dt][4 * g + 3]);
                const int q = q0 + sp * 32 + 8 * g + 4 * hi;
                *(uint2*)(numpart + (size_t)(chunk * 64 + d) * NH + q) = u2;
            }
        }
}

// ---------------------------------------------------------------------------
// Kernel 3: finalize = Vsum + 2*chunk-sum + measure (den-free) + TT out proj.
// measure = num^2 / (sum_d num^2 + EPS*NH^2)
// ---------------------------------------------------------------------------
__global__ __launch_bounds__(256) void finalize(
    const ushort* __restrict__ numpart, const float* __restrict__ Vsum,
    const float* __restrict__ oA, const float* __restrict__ oB,
    const float* __restrict__ ob, float* __restrict__ out)
{
    __shared__ float L[8][NCHUNK][64];   // [qsub][chunk][d]
    __shared__ float csum[8];
    __shared__ float wred[4][4];
    __shared__ float tvals[4];

    const int n = blockIdx.x, t = threadIdx.x;
    const int wid = t >> 6, lane = t & 63;

    #pragma unroll
    for (int ci = 0; ci < 2; ++ci) {
        const int cc = (t >> 6) + ci * 4;
        const int dd = t & 63;
        const uint4 u = *(const uint4*)(numpart + (size_t)(cc * 64 + dd) * NH + n * 8);
        L[0][cc][dd] = h2f((ushort)(u.x & 0xffff));
        L[1][cc][dd] = h2f((ushort)(u.x >> 16));
        L[2][cc][dd] = h2f((ushort)(u.y & 0xffff));
        L[3][cc][dd] = h2f((ushort)(u.y >> 16));
        L[4][cc][dd] = h2f((ushort)(u.z & 0xffff));
        L[5][cc][dd] = h2f((ushort)(u.z >> 16));
        L[6][cc][dd] = h2f((ushort)(u.w & 0xffff));
        L[7][cc][dd] = h2f((ushort)(u.w >> 16));
    }
    __syncthreads();

    const float vs = Vsum[lane];
    float b0 = 0.f, b1 = 0.f;
    #pragma unroll
    for (int c = 0; c < NCHUNK; ++c) { b0 += L[wid][c][lane]; b1 += L[wid + 4][c][lane]; }
    const float a0 = vs + 2.f * b0;
    const float a1 = vs + 2.f * b1;

    float s0 = a0 * a0, s1 = a1 * a1;
    #pragma unroll
    for (int off = 32; off; off >>= 1) { s0 += __shfl_xor(s0, off); s1 += __shfl_xor(s1, off); }
    if (lane == 0) { csum[wid] = s0; csum[4 + wid] = s1; }
    __syncthreads();

    const float m0 = a0 * a0 / (csum[wid] + EPSDEN2);
    const float m1 = a1 * a1 / (csum[4 + wid] + EPSDEN2);

    float p[4];
    #pragma unroll
    for (int r = 0; r < 4; ++r) p[r] = m0 * oB[r * DIM + t] + m1 * oB[r * DIM + t + 256];
    #pragma unroll
    for (int r = 0; r < 4; ++r) {
        #pragma unroll
        for (int off = 32; off; off >>= 1) p[r] += __shfl_xor(p[r], off);
    }
    if (lane == 0) {
        #pragma unroll
        for (int r = 0; r < 4; ++r) wred[wid][r] = p[r];
    }
    __syncthreads();
    if (t < 4) tvals[t] = wred[0][t] + wred[1][t] + wred[2][t] + wred[3][t];
    __syncthreads();

    #pragma unroll
    for (int h = 0; h < 2; ++h) {
        const int o = t + h * 256;
        float y = ob[o];
        #pragma unroll
        for (int r = 0; r < 4; ++r) y += tvals[r] * oA[o * RANK + r];
        out[n * DIM + o] = y;
    }
}

// ---------------------------------------------------------------------------
extern "C" void kernel_launch(void* const* d_in, const int* in_sizes, int n_in,
                              void* d_out, int out_size, void* d_ws, size_t ws_size,
                              hipStream_t stream) {
    const float* x  = (const float*)d_in[0];
    const float* qA = (const float*)d_in[1];
    const float* qB = (const float*)d_in[2];
    const float* qb = (const float*)d_in[3];
    const float* kA = (const float*)d_in[4];
    const float* kB = (const float*)d_in[5];
    const float* kb = (const float*)d_in[6];
    const float* vA = (const float*)d_in[7];
    const float* vB = (const float*)d_in[8];
    const float* vb = (const float*)d_in[9];
    const float* oA = (const float*)d_in[10];
    const float* oB = (const float*)d_in[11];
    const float* ob = (const float*)d_in[12];

    // ws: qq 2MB | kq 2MB | vvT 2MB | numpart fp16 [8][64][NH] 16MB | Vsum 256B
    ushort* qq_b    = (ushort*)d_ws;
    ushort* kq_b    = qq_b + (size_t)NH * DH;
    ushort* vvT     = kq_b + (size_t)NH * DH;
    ushort* numpart = vvT + (size_t)NH * DH;
    float*  Vsum    = (float*)(numpart + (size_t)NCHUNK * DH * NH);
    float*  out     = (float*)d_out;

    proj_qkv<<<NROW, 256, 0, stream>>>(x, qA, qB, qb, kA, kB, kb, vA, vB, vb, qq_b, kq_b, vvT);
    vsum_kernel<<<DH, 256, 0, stream>>>(vvT, Vsum);
    attn_kernel<<<64 * NCHUNK, 256, 0, stream>>>(qq_b, kq_b, vvT, numpart);
    finalize<<<NROW, 256, 0, stream>>>(numpart, Vsum, oA, oB, ob, out);
}

// Round 8
// 126.619 us; speedup vs baseline: 1.0875x; 1.0184x over previous
//
#include <hip/hip_runtime.h>
#include <math.h>

#define DIM    512
#define RANK   4
#define NROW   2048   // BATCH * SEQ
#define DH     64
#define NH     16384  // NROW * HEADS
#define EPS    1e-8f
#define EPSDEN2 2.68435456f   // EPS * NH^2 (den ~= NH; measure-cancellation, r3)
// kq pre-scale: y = s*(1+lam)/16, lam = 1/512 (minimax absorb of x^3/6 over |x|<=1/8)
#define KSCALE 0.0626220703125f

typedef short  bf16x8 __attribute__((ext_vector_type(8)));
typedef ushort u16x8  __attribute__((ext_vector_type(8)));
typedef float  f32x16 __attribute__((ext_vector_type(16)));

static __device__ __forceinline__ ushort f2bf(float f) {
    uint u = __float_as_uint(f);
    u += 0x7FFFu + ((u >> 16) & 1u);   // round-to-nearest-even
    return (ushort)(u >> 16);
}
static __device__ __forceinline__ float bf2f(ushort u) {
    return __uint_as_float((uint)u << 16);
}
static __device__ __forceinline__ uint cvtpk_bf16(float a, float b) {
    uint r;
    asm("v_cvt_pk_bf16_f32 %0, %1, %2" : "=v"(r) : "v"(a), "v"(b));
    return r;
}
static __device__ __forceinline__ void pl32swap(uint& a, uint& b) {
    asm("v_permlane32_swap_b32 %0, %1" : "+v"(a), "+v"(b));
}
static __device__ __forceinline__ uint pkh2(float a, float b) {
    _Float16 ha = (_Float16)a, hb = (_Float16)b;
    return (uint)__builtin_bit_cast(ushort, ha) | ((uint)__builtin_bit_cast(ushort, hb) << 16);
}
static __device__ __forceinline__ float h2f(ushort u) {
    return (float)__builtin_bit_cast(_Float16, u);
}
// barrier with LDS-visibility wait only (prefetch global loads stay in flight)
static __device__ __forceinline__ void barrier_lgkm() {
    asm volatile("s_waitcnt lgkmcnt(0)" ::: "memory");
    __builtin_amdgcn_s_barrier();
}

// ---------------------------------------------------------------------------
// Kernel 1: TT projections q,k,v + L2-normalize q,k per head-row.
// kq additionally scaled by KSCALE so the S-MFMA directly yields y.
// Outputs: qq_b/kq_b bf16 [NH][DH], vvT bf16 [DH][NH].
// ---------------------------------------------------------------------------
__global__ __launch_bounds__(256) void proj_qkv(
    const float* __restrict__ x,
    const float* __restrict__ qA, const float* __restrict__ qB, const float* __restrict__ qb,
    const float* __restrict__ kA, const float* __restrict__ kB, const float* __restrict__ kb,
    const float* __restrict__ vA, const float* __restrict__ vB, const float* __restrict__ vb,
    ushort* __restrict__ qq_b, ushort* __restrict__ kq_b, ushort* __restrict__ vvT)
{
    __shared__ float qrow[DIM], krow[DIM], vrowS[DIM];
    __shared__ float wred[4][12];
    __shared__ float tvals[12];
    __shared__ float norms[16];

    const int n = blockIdx.x, t = threadIdx.x;
    const int wid = t >> 6, lane = t & 63;

    const float x0 = x[n * DIM + t];
    const float x1 = x[n * DIM + t + 256];

    float p[12];
    #pragma unroll
    for (int r = 0; r < 4; ++r) {
        p[r]     = x0 * qB[r * DIM + t] + x1 * qB[r * DIM + t + 256];
        p[4 + r] = x0 * kB[r * DIM + t] + x1 * kB[r * DIM + t + 256];
        p[8 + r] = x0 * vB[r * DIM + t] + x1 * vB[r * DIM + t + 256];
    }
    #pragma unroll
    for (int i = 0; i < 12; ++i) {
        #pragma unroll
        for (int off = 32; off; off >>= 1) p[i] += __shfl_xor(p[i], off);
    }
    if (lane == 0) {
        #pragma unroll
        for (int i = 0; i < 12; ++i) wred[wid][i] = p[i];
    }
    __syncthreads();
    if (t < 12) tvals[t] = wred[0][t] + wred[1][t] + wred[2][t] + wred[3][t];
    __syncthreads();

    float tq[4], tk[4], tv[4];
    #pragma unroll
    for (int r = 0; r < 4; ++r) { tq[r] = tvals[r]; tk[r] = tvals[4 + r]; tv[r] = tvals[8 + r]; }

    #pragma unroll
    for (int h = 0; h < 2; ++h) {
        const int o = t + h * 256;
        float yq = qb[o], yk = kb[o], yv = vb[o];
        #pragma unroll
        for (int r = 0; r < 4; ++r) {
            yq += tq[r] * qA[o * RANK + r];
            yk += tk[r] * kA[o * RANK + r];
            yv += tv[r] * vA[o * RANK + r];
        }
        qrow[o] = yq; krow[o] = yk; vrowS[o] = yv;
    }
    __syncthreads();

    {
        const int c = t >> 5, i2 = t & 31;
        const float a  = qrow[c * 64 + i2], b2 = qrow[c * 64 + i2 + 32];
        const float ak = krow[c * 64 + i2], bk = krow[c * 64 + i2 + 32];
        float s  = a * a + b2 * b2;
        float sk = ak * ak + bk * bk;
        #pragma unroll
        for (int off = 16; off; off >>= 1) { s += __shfl_xor(s, off); sk += __shfl_xor(sk, off); }
        if (i2 == 0) { norms[c] = sqrtf(s); norms[8 + c] = sqrtf(sk); }
    }
    __syncthreads();

    #pragma unroll
    for (int h = 0; h < 2; ++h) {
        const int o = t + h * 256;
        const int c = o >> 6;
        qq_b[n * DIM + o] = f2bf(qrow[o] / (norms[c] + EPS));
        kq_b[n * DIM + o] = f2bf(krow[o] / (norms[8 + c] + EPS) * KSCALE);
    }

    // vvT[d][n*8 + j] = vrowS[j*64 + d]
    if (t < 64) {
        uint pk[4];
        #pragma unroll
        for (int i = 0; i < 4; ++i) {
            pk[i] = (uint)f2bf(vrowS[(2 * i) * 64 + t])
                  | ((uint)f2bf(vrowS[(2 * i + 1) * 64 + t]) << 16);
        }
        uint4 u4; u4.x = pk[0]; u4.y = pk[1]; u4.z = pk[2]; u4.w = pk[3];
        *(uint4*)((char*)vvT + (size_t)t * (NH * 2) + (size_t)n * 16) = u4;
    }
}

// ---------------------------------------------------------------------------
// Kernel 1b: Vsum[d] = sum over all NH keys of v[key][d]
// ---------------------------------------------------------------------------
__global__ __launch_bounds__(256) void vsum_kernel(
    const ushort* __restrict__ vvT, float* __restrict__ Vsum)
{
    __shared__ float red[4];
    const int d = blockIdx.x, t = threadIdx.x;
    const int wid = t >> 6, lane = t & 63;
    float s = 0.f;
    #pragma unroll
    for (int j = 0; j < 8; ++j) {
        const u16x8 u = *(const u16x8*)(vvT + (size_t)d * NH + (size_t)(j * 256 + t) * 8);
        #pragma unroll
        for (int e = 0; e < 8; ++e) s += bf2f(u[e]);
    }
    #pragma unroll
    for (int off = 32; off; off >>= 1) s += __shfl_xor(s, off);
    if (lane == 0) red[wid] = s;
    __syncthreads();
    if (t == 0) Vsum[d] = red[0] + red[1] + red[2] + red[3];
}

// ---------------------------------------------------------------------------
// Kernel 2: MFMA flash attention. Weight w = 1 + 2*(y + y^2), y = s(1+lam)/16
// (the "1" is Vsum, folded in finalize; the 2 is applied in finalize).
// 4 waves x 64 q (2 strips) = 256 q/block; grid = 64 q-blocks x (1<<LOG2NC)
// chunks. 32-key steps; K tile [32][128B], V tile [32][128B] (two d-halves
// per row), XOR-swizzled, double-buffered (16 KB LDS total -> 4 blocks/CU
// at LOG2NC=4 => 16 waves/CU, 2x the r7 occupancy).
// Reg-staged with s+2 prefetch; one lgkm-barrier per step.
// Writes fp16 numpart[chunk][d][q].
// ---------------------------------------------------------------------------
template<int LOG2NC>
__global__ __launch_bounds__(256, 2) void attn_kernel(
    const ushort* __restrict__ qq_b, const ushort* __restrict__ kq_b,
    const ushort* __restrict__ vvT, ushort* __restrict__ numpart)
{
    constexpr int KCH = NH >> LOG2NC;     // keys per block
    constexpr int NST = KCH >> 5;         // 32-key steps

    __shared__ __align__(16) char smem[2][8192];   // [buf][ K 4KB | V 4KB ]

    const int t = threadIdx.x;
    const int w = t >> 6, l = t & 63;
    const int l31 = l & 31, hi = l >> 5;
    const int chunk = blockIdx.x & ((1 << LOG2NC) - 1);
    const int q0 = (blockIdx.x >> LOG2NC) * 256 + w * 64;
    const int kbase = chunk * KCH;

    // staging: thread t covers (row = t>>3, 16B slot = t&7) for K and V
    const int sr = t >> 3, ssl = t & 7;
    const int kwo = sr * 128 + ((ssl ^ (sr & 7)) << 4);
    const int vwo = 4096 + kwo;
    const size_t kgo = (size_t)(kbase + sr) * 128 + (ssl << 4);
    // V LDS row r: [d=r keys 0..31 | d=r+32 keys 0..31]
    const size_t vgo = (size_t)(sr + 32 * (ssl >> 2)) * (NH * 2)
                     + (size_t)kbase * 2 + ((size_t)(ssl & 3) << 4);

    // Q fragments (B-operand): strip sp, lane: col q = q0+sp*32+l31,
    // k-elems w16*16 + hi*8 .. +8
    bf16x8 Qf[2][4];
    #pragma unroll
    for (int sp = 0; sp < 2; ++sp)
        #pragma unroll
        for (int w16 = 0; w16 < 4; ++w16)
            Qf[sp][w16] = *(const bf16x8*)((const char*)qq_b
                + (size_t)(q0 + sp * 32 + l31) * 128 + w16 * 32 + hi * 16);

    f32x16 acc[2][2];
    #pragma unroll
    for (int sp = 0; sp < 2; ++sp)
        #pragma unroll
        for (int dt = 0; dt < 2; ++dt)
            #pragma unroll
            for (int r = 0; r < 16; ++r) acc[sp][dt][r] = 0.f;

    // prologue: stage step 0, prefetch step 1 into regs
    uint4 kst = *(const uint4*)((const char*)kq_b + kgo);
    uint4 vst = *(const uint4*)((const char*)vvT + vgo);
    *(uint4*)(smem[0] + kwo) = kst;
    *(uint4*)(smem[0] + vwo) = vst;
    kst = *(const uint4*)((const char*)kq_b + kgo + 4096);
    vst = *(const uint4*)((const char*)vvT + vgo + 64);
    barrier_lgkm();

    for (int s = 0; s < NST; ++s) {
        const char* B = smem[s & 1];
        if (s + 1 < NST) {                        // write step s+1's staged regs
            char* D = (char*)smem[(s & 1) ^ 1];
            *(uint4*)(D + kwo) = kst;
            *(uint4*)(D + vwo) = vst;
        }
        if (s + 2 < NST) {                        // early-issue step s+2's loads
            kst = *(const uint4*)((const char*)kq_b + kgo + (size_t)(s + 2) * 4096);
            vst = *(const uint4*)((const char*)vvT + vgo + (size_t)(s + 2) * 64);
        }

        // K A-frags: lane: key-row l31, dh-slice w16*16+hi*8
        bf16x8 kf[4];
        #pragma unroll
        for (int w16 = 0; w16 < 4; ++w16)
            kf[w16] = *(const bf16x8*)(B + l31 * 128
                      + ((((w16 << 1) | hi) ^ (l31 & 7)) << 4));

        union U { uint u[4]; bf16x8 v; };
        U pa[2][2];
        #pragma unroll
        for (int sp = 0; sp < 2; ++sp) {
            f32x16 st;
            #pragma unroll
            for (int r = 0; r < 16; ++r) st[r] = 0.f;
            __builtin_amdgcn_s_setprio(1);
            #pragma unroll
            for (int w16 = 0; w16 < 4; ++w16)
                st = __builtin_amdgcn_mfma_f32_32x32x16_bf16(kf[w16], Qf[sp][w16], st, 0, 0, 0);
            __builtin_amdgcn_s_setprio(0);

            // P'' = y + y^2 = fma(y,y,y): ONE VALU op per element
            uint pk[8];
            #pragma unroll
            for (int j = 0; j < 8; ++j)
                pk[j] = cvtpk_bf16(fmaf(st[2 * j], st[2 * j], st[2 * j]),
                                   fmaf(st[2 * j + 1], st[2 * j + 1], st[2 * j + 1]));
            pl32swap(pk[0], pk[2]); pl32swap(pk[1], pk[3]);
            pl32swap(pk[4], pk[6]); pl32swap(pk[5], pk[7]);
            #pragma unroll
            for (int j = 0; j < 4; ++j) { pa[sp][0].u[j] = pk[j]; pa[sp][1].u[j] = pk[4 + j]; }
        }

        __builtin_amdgcn_s_setprio(1);
        #pragma unroll
        for (int kw = 0; kw < 2; ++kw) {
            #pragma unroll
            for (int dt = 0; dt < 2; ++dt) {
                // V B-frag: lane: col d = dt*32+l31, keys kw*16+hi*8..+8
                const bf16x8 vf = *(const bf16x8*)(B + 4096 + l31 * 128
                    + ((((dt << 2) | (kw << 1) | hi) ^ (l31 & 7)) << 4));
                #pragma unroll
                for (int sp = 0; sp < 2; ++sp)
                    acc[sp][dt] = __builtin_amdgcn_mfma_f32_32x32x16_bf16(pa[sp][kw].v, vf, acc[sp][dt], 0, 0, 0);
            }
        }
        __builtin_amdgcn_s_setprio(0);
        barrier_lgkm();
    }

    // epilogue: acc D[q][d]: col d = dt*32+l31; regs 4g..4g+3 -> q = base+8g+4hi+0..3
    #pragma unroll
    for (int sp = 0; sp < 2; ++sp)
        #pragma unroll
        for (int dt = 0; dt < 2; ++dt) {
            const int d = dt * 32 + l31;
            #pragma unroll
            for (int g = 0; g < 4; ++g) {
                uint2 u2;
                u2.x = pkh2(acc[sp][dt][4 * g],     acc[sp][dt][4 * g + 1]);
                u2.y = pkh2(acc[sp][dt][4 * g + 2], acc[sp][dt][4 * g + 3]);
                const int q = q0 + sp * 32 + 8 * g + 4 * hi;
                *(uint2*)(numpart + (size_t)(chunk * 64 + d) * NH + q) = u2;
            }
        }
}

// ---------------------------------------------------------------------------
// Kernel 3: finalize = Vsum + 2*chunk-sum + measure (den-free) + TT out proj.
// measure = num^2 / (sum_d num^2 + EPS*NH^2)
// ---------------------------------------------------------------------------
__global__ __launch_bounds__(256) void finalize(
    const ushort* __restrict__ numpart, const float* __restrict__ Vsum,
    const float* __restrict__ oA, const float* __restrict__ oB,
    const float* __restrict__ ob, float* __restrict__ out, int nchunk)
{
    __shared__ float L[8][16][64];   // [qsub][chunk][d]
    __shared__ float csum[8];
    __shared__ float wred[4][4];
    __shared__ float tvals[4];

    const int n = blockIdx.x, t = threadIdx.x;
    const int wid = t >> 6, lane = t & 63;

    for (int cc = t >> 6; cc < nchunk; cc += 4) {
        const int dd = t & 63;
        const uint4 u = *(const uint4*)(numpart + (size_t)(cc * 64 + dd) * NH + n * 8);
        L[0][cc][dd] = h2f((ushort)(u.x & 0xffff));
        L[1][cc][dd] = h2f((ushort)(u.x >> 16));
        L[2][cc][dd] = h2f((ushort)(u.y & 0xffff));
        L[3][cc][dd] = h2f((ushort)(u.y >> 16));
        L[4][cc][dd] = h2f((ushort)(u.z & 0xffff));
        L[5][cc][dd] = h2f((ushort)(u.z >> 16));
        L[6][cc][dd] = h2f((ushort)(u.w & 0xffff));
        L[7][cc][dd] = h2f((ushort)(u.w >> 16));
    }
    __syncthreads();

    const float vs = Vsum[lane];
    float b0 = 0.f, b1 = 0.f;
    for (int c = 0; c < nchunk; ++c) { b0 += L[wid][c][lane]; b1 += L[wid + 4][c][lane]; }
    const float a0 = vs + 2.f * b0;
    const float a1 = vs + 2.f * b1;

    float s0 = a0 * a0, s1 = a1 * a1;
    #pragma unroll
    for (int off = 32; off; off >>= 1) { s0 += __shfl_xor(s0, off); s1 += __shfl_xor(s1, off); }
    if (lane == 0) { csum[wid] = s0; csum[4 + wid] = s1; }
    __syncthreads();

    const float m0 = a0 * a0 / (csum[wid] + EPSDEN2);
    const float m1 = a1 * a1 / (csum[4 + wid] + EPSDEN2);

    float p[4];
    #pragma unroll
    for (int r = 0; r < 4; ++r) p[r] = m0 * oB[r * DIM + t] + m1 * oB[r * DIM + t + 256];
    #pragma unroll
    for (int r = 0; r < 4; ++r) {
        #pragma unroll
        for (int off = 32; off; off >>= 1) p[r] += __shfl_xor(p[r], off);
    }
    if (lane == 0) {
        #pragma unroll
        for (int r = 0; r < 4; ++r) wred[wid][r] = p[r];
    }
    __syncthreads();
    if (t < 4) tvals[t] = wred[0][t] + wred[1][t] + wred[2][t] + wred[3][t];
    __syncthreads();

    #pragma unroll
    for (int h = 0; h < 2; ++h) {
        const int o = t + h * 256;
        float y = ob[o];
        #pragma unroll
        for (int r = 0; r < 4; ++r) y += tvals[r] * oA[o * RANK + r];
        out[n * DIM + o] = y;
    }
}

// ---------------------------------------------------------------------------
extern "C" void kernel_launch(void* const* d_in, const int* in_sizes, int n_in,
                              void* d_out, int out_size, void* d_ws, size_t ws_size,
                              hipStream_t stream) {
    const float* x  = (const float*)d_in[0];
    const float* qA = (const float*)d_in[1];
    const float* qB = (const float*)d_in[2];
    const float* qb = (const float*)d_in[3];
    const float* kA = (const float*)d_in[4];
    const float* kB = (const float*)d_in[5];
    const float* kb = (const float*)d_in[6];
    const float* vA = (const float*)d_in[7];
    const float* vB = (const float*)d_in[8];
    const float* vb = (const float*)d_in[9];
    const float* oA = (const float*)d_in[10];
    const float* oB = (const float*)d_in[11];
    const float* ob = (const float*)d_in[12];

    // ws: qq 2MB | kq 2MB | vvT 2MB | numpart fp16 [nc][64][NH] | Vsum 256B
    // nc=16 needs 6291456 + 33554432 + 256 = 39.85 MB; guard and fall back to 8.
    const bool use16 = ws_size >= (size_t)39846400;
    const int nchunk = use16 ? 16 : 8;

    ushort* qq_b    = (ushort*)d_ws;
    ushort* kq_b    = qq_b + (size_t)NH * DH;
    ushort* vvT     = kq_b + (size_t)NH * DH;
    ushort* numpart = vvT + (size_t)NH * DH;
    float*  Vsum    = (float*)(numpart + (size_t)nchunk * DH * NH);
    float*  out     = (float*)d_out;

    proj_qkv<<<NROW, 256, 0, stream>>>(x, qA, qB, qb, kA, kB, kb, vA, vB, vb, qq_b, kq_b, vvT);
    vsum_kernel<<<DH, 256, 0, stream>>>(vvT, Vsum);
    if (use16)
        attn_kernel<4><<<64 * 16, 256, 0, stream>>>(qq_b, kq_b, vvT, numpart);
    else
        attn_kernel<3><<<64 * 8, 256, 0, stream>>>(qq_b, kq_b, vvT, numpart);
    finalize<<<NROW, 256, 0, stream>>>(numpart, Vsum, oA, oB, ob, out, nchunk);
}